// Round 3
// baseline (677.699 us; speedup 1.0000x reference)
//
#include <hip/hip_runtime.h>

#define NTH 180
#define NPH 360
#define BATCH 1024
#define NBLK 2048            // one block per (b, channel) slab
#define NTHREADS 256

// Per-slab: 64800 floats = 16200 float4 = 63*256 + 72
#define SLAB_F4 16200
#define FULL_ITERS 63
#define TAIL_THREADS 72

// clip(log(x), -100) in log2 domain: -100/ln2
#define LOG2_CLIP (-144.26950408889634f)
#define LN2F 0.6931471805599453f

// Phase A: block bi streams its own contiguous slab (the (b,c) grid it owns),
//          summing -clip(log1p(-p),-100) (accumulated as log2, scaled at end).
// Phase B: same block computes the Gaussian-label window term on that slab
//          (window data just streamed -> L2-hot). Exact to ~5e-32 at R=12.
__global__ __launch_bounds__(NTHREADS) void fused_kernel(
    const float* __restrict__ probs, const float* __restrict__ gt_u,
    const float* __restrict__ gt_r, float2* __restrict__ partial) {
    const int tid = threadIdx.x;
    const float4* __restrict__ slab4 =
        (const float4*)probs + (int)blockIdx.x * SLAB_F4;

    // ---- Phase A: dense streaming reduction over this slab ----
    float sd = 0.0f;
    #pragma unroll 4
    for (int it = 0; it < FULL_ITERS; ++it) {
        float4 v = slab4[tid + it * NTHREADS];
        sd += fmaxf(__log2f(1.0f - v.x), LOG2_CLIP);
        sd += fmaxf(__log2f(1.0f - v.y), LOG2_CLIP);
        sd += fmaxf(__log2f(1.0f - v.z), LOG2_CLIP);
        sd += fmaxf(__log2f(1.0f - v.w), LOG2_CLIP);
    }
    if (tid < TAIL_THREADS) {
        float4 v = slab4[tid + FULL_ITERS * NTHREADS];
        sd += fmaxf(__log2f(1.0f - v.x), LOG2_CLIP);
        sd += fmaxf(__log2f(1.0f - v.y), LOG2_CLIP);
        sd += fmaxf(__log2f(1.0f - v.z), LOG2_CLIP);
        sd += fmaxf(__log2f(1.0f - v.w), LOG2_CLIP);
    }

    // ---- Phase B: label window term for (b,c) = blockIdx ----
    int b = blockIdx.x >> 1;
    int c = blockIdx.x & 1;
    const float* g = (c == 0) ? gt_u : gt_r;
    float gx = g[b * 3 + 0], gy = g[b * 3 + 1], gz = g[b * 3 + 2];

    float theta = acosf(fminf(fmaxf(gz, -1.0f), 1.0f));
    float phi = atan2f(gy, gx);
    if (phi < 0.0f) phi += 6.283185307179586f;
    int t = (int)(theta * (1.0f / 3.14159265358979323846f) * (float)NTH);
    t = min(max(t, 0), NTH - 1);
    int pb = (int)(phi * (1.0f / 6.283185307179586f) * (float)NPH);
    pb = min(max(pb, 0), NPH - 1);

    const int R = 12;
    int i0 = max(0, t - R), i1 = min(NTH - 1, t + R);
    int j0 = max(0, pb - R), j1 = min(NPH - 1, pb + R);

    // Separable normalizer over the clipped window (ref mask never binds at R=12)
    float zt = 0.0f, zp = 0.0f;
    for (int i = i0; i <= i1; ++i) { float d = (float)(i - t);  zt += __expf(-0.5f * d * d); }
    for (int j = j0; j <= j1; ++j) { float d = (float)(j - pb); zp += __expf(-0.5f * d * d); }
    float invZ = 1.0f / (zt * zp);

    const float* __restrict__ P = (const float*)slab4;
    int nj = j1 - j0 + 1;
    int npts = (i1 - i0 + 1) * nj;
    float sl = 0.0f;
    for (int k = tid; k < npts; k += NTHREADS) {
        int i = i0 + k / nj;
        int j = j0 + k % nj;
        float di = (float)(i - t), dj = (float)(j - pb);
        float w = __expf(-0.5f * (di * di + dj * dj));
        float pv = P[i * NPH + j];
        // p in [1e-4, 1-1e-4] -> neither log clips; lq-lp = log((1-p)/p)
        sl += w * __logf((1.0f - pv) / pv);
    }

    // ---- combined block reduction of (sd, sl) ----
    #pragma unroll
    for (int off = 32; off > 0; off >>= 1) {
        sd += __shfl_down(sd, off);
        sl += __shfl_down(sl, off);
    }
    __shared__ float wsd[4], wsl[4];
    int lane = tid & 63, wid = tid >> 6;
    if (lane == 0) { wsd[wid] = sd; wsl[wid] = sl; }
    __syncthreads();
    if (tid == 0) {
        float bd = wsd[0] + wsd[1] + wsd[2] + wsd[3];
        float bl = wsl[0] + wsl[1] + wsl[2] + wsl[3];
        partial[blockIdx.x] = make_float2(-LN2F * bd, invZ * bl);
    }
}

// Reduce 2048 float2 partials in double, finalize the scalar loss.
__global__ __launch_bounds__(NTHREADS) void reduce_kernel(
    const float2* __restrict__ partial, float* __restrict__ out) {
    double s = 0.0;
    for (int i = threadIdx.x; i < NBLK; i += NTHREADS) {
        float2 v = partial[i];
        s += (double)v.x + (double)v.y;
    }
    #pragma unroll
    for (int off = 32; off > 0; off >>= 1) s += __shfl_down(s, off);
    __shared__ double wsum[4];
    int lane = threadIdx.x & 63, wid = threadIdx.x >> 6;
    if (lane == 0) wsum[wid] = s;
    __syncthreads();
    if (threadIdx.x == 0) {
        double tot = wsum[0] + wsum[1] + wsum[2] + wsum[3];
        double denom = (double)BATCH * (double)NTH * (double)NPH;
        out[0] = (float)(tot / denom);   // LOSS_WEIGHT = 1
    }
}

extern "C" void kernel_launch(void* const* d_in, const int* in_sizes, int n_in,
                              void* d_out, int out_size, void* d_ws, size_t ws_size,
                              hipStream_t stream) {
    const float* probs = (const float*)d_in[0];
    const float* gt_u  = (const float*)d_in[1];
    const float* gt_r  = (const float*)d_in[2];
    float* out = (float*)d_out;
    float2* partial = (float2*)d_ws;     // 2048 * 8 B = 16 KB, fully overwritten

    fused_kernel<<<NBLK, NTHREADS, 0, stream>>>(probs, gt_u, gt_r, partial);
    reduce_kernel<<<1, NTHREADS, 0, stream>>>(partial, out);
}